// Round 1
// baseline (65003.235 us; speedup 1.0000x reference)
//
#include <hip/hip_runtime.h>
#include <hip/hip_bf16.h>
#include <cstddef>
#include <type_traits>

// LSTM: T=512, B=64, D=1024, H=1024
//   xg = x @ Wx^T + bh   (one big GEMM, done up front into d_ws)
//   per step t: gates = xg[t] + h_{t-1} @ Wh^T ; elementwise LSTM cell
// outputs[t] = h_t lives directly in d_out, so h history needs no scratch.

#define T_DIM 512
#define B_DIM 64
#define H_DIM 1024
#define G_DIM 4096

__device__ __forceinline__ float sigmoidf_(float x) {
  return 1.0f / (1.0f + expf(-x));
}

// ---------------- GEMM1: xg[m][n] = sum_k x[m][k]*Wx[n][k] + bh[n] ----------
// M = 32768 (t*64+b), N = 4096, K = 1024. Both operands K-contiguous (NT).
// 64x64 block tile, 256 threads, 4x4 per thread, k-tile 16.
template <typename OUT_T>
__global__ __launch_bounds__(256) void xg_gemm_kernel(
    const float* __restrict__ A,    // x  [M][1024]
    const float* __restrict__ Bw,   // Wx [4096][1024]
    const float* __restrict__ bh,   // [4096]
    OUT_T* __restrict__ C) {        // xg [M][4096]
  __shared__ float As[16][68];      // [k][m], pad 68 keeps 16B align + low conflicts
  __shared__ float Bs[16][68];      // [k][n]
  const int tid = threadIdx.x;
  const size_t m0 = (size_t)blockIdx.x * 64;
  const int n0 = blockIdx.y * 64;
  const int tx = tid & 15;          // n sub-tile
  const int ty = tid >> 4;          // m sub-tile
  const int lm = tid >> 2;          // load row 0..63
  const int lk = (tid & 3) * 4;     // load k chunk 0,4,8,12
  float acc[4][4] = {};
  for (int k0 = 0; k0 < 1024; k0 += 16) {
    __syncthreads();
    float4 av = *(const float4*)&A[(m0 + lm) * 1024 + k0 + lk];
    float4 bv = *(const float4*)&Bw[(size_t)(n0 + lm) * 1024 + k0 + lk];
    As[lk + 0][lm] = av.x; As[lk + 1][lm] = av.y;
    As[lk + 2][lm] = av.z; As[lk + 3][lm] = av.w;
    Bs[lk + 0][lm] = bv.x; Bs[lk + 1][lm] = bv.y;
    Bs[lk + 2][lm] = bv.z; Bs[lk + 3][lm] = bv.w;
    __syncthreads();
#pragma unroll
    for (int k = 0; k < 16; ++k) {
      float a[4], b[4];
      *(float4*)a = *(const float4*)&As[k][ty * 4];
      *(float4*)b = *(const float4*)&Bs[k][tx * 4];
#pragma unroll
      for (int i = 0; i < 4; ++i)
#pragma unroll
        for (int j = 0; j < 4; ++j)
          acc[i][j] = fmaf(a[i], b[j], acc[i][j]);
    }
  }
  float4 bhv = *(const float4*)&bh[n0 + tx * 4];
  float bb[4] = {bhv.x, bhv.y, bhv.z, bhv.w};
#pragma unroll
  for (int i = 0; i < 4; ++i) {
    size_t row = m0 + ty * 4 + i;
    if constexpr (std::is_same_v<OUT_T, float>) {
      float4 v = make_float4(acc[i][0] + bb[0], acc[i][1] + bb[1],
                             acc[i][2] + bb[2], acc[i][3] + bb[3]);
      *(float4*)&C[row * 4096 + n0 + tx * 4] = v;
    } else {
      __hip_bfloat16 tmp[4];
#pragma unroll
      for (int j = 0; j < 4; ++j) tmp[j] = __float2bfloat16(acc[i][j] + bb[j]);
      *reinterpret_cast<uint2*>(&C[row * 4096 + n0 + tx * 4]) =
          *reinterpret_cast<uint2*>(tmp);
    }
  }
}

// ---------------- per-step recurrent kernel --------------------------------
// gates[b][g*1024+j] = xg[t][b][g*1024+j] + sum_k h[b][k]*Wh[g*1024+j][k]
// 128 blocks: block owns j in [j0, j0+8), all 4 gates, all 64 batches.
// thread: jj = tid&7, b0 = tid>>3; computes (b0, b0+32) x 4 gates for j0+jj,
// so each thread holds i,f,g,o of its (b,j) -> cell update fully local.
template <typename XG_T>
__global__ __launch_bounds__(256) void lstm_step_kernel(
    const XG_T* __restrict__ xg,   // [T*B][4096] (bh already folded in)
    const float* __restrict__ Wh,  // [4096][1024]
    float* __restrict__ out,       // [T][B][H]; out[t-1] is h_prev
    float* __restrict__ c,         // [B][H] running cell state (ws)
    int t) {
  __shared__ float hs[64][68];     // h tile   [b][k], pad 68: 16B-aligned rows
  __shared__ float wt[32][64];     // Wh rows  [gate*8+jjj][k]
  const int tid = threadIdx.x;
  const int j0 = blockIdx.x * 8;
  const int jj = tid & 7;
  const int b0 = tid >> 3;         // 0..31
  float acc[2][4] = {};
  if (t > 0) {
    const float* __restrict__ hprev = out + (size_t)(t - 1) * (B_DIM * H_DIM);
    for (int k0 = 0; k0 < 1024; k0 += 64) {
      __syncthreads();
#pragma unroll
      for (int i = 0; i < 16; ++i) {
        int e = tid + 256 * i;
        int bb = e >> 6, kk = e & 63;
        hs[bb][kk] = hprev[bb * 1024 + k0 + kk];
      }
#pragma unroll
      for (int i = 0; i < 8; ++i) {
        int e = tid + 256 * i;
        int r = e >> 6, kk = e & 63;   // r = gate*8 + jjj
        wt[r][kk] = Wh[(size_t)((r >> 3) * 1024 + j0 + (r & 7)) * 1024 + k0 + kk];
      }
      __syncthreads();
#pragma unroll
      for (int kq = 0; kq < 16; ++kq) {
        float4 h0 = *(const float4*)&hs[b0][kq * 4];
        float4 h1 = *(const float4*)&hs[b0 + 32][kq * 4];
#pragma unroll
        for (int u = 0; u < 4; ++u) {
          float4 wv = *(const float4*)&wt[u * 8 + jj][kq * 4];
          acc[0][u] = fmaf(h0.x, wv.x, acc[0][u]);
          acc[0][u] = fmaf(h0.y, wv.y, acc[0][u]);
          acc[0][u] = fmaf(h0.z, wv.z, acc[0][u]);
          acc[0][u] = fmaf(h0.w, wv.w, acc[0][u]);
          acc[1][u] = fmaf(h1.x, wv.x, acc[1][u]);
          acc[1][u] = fmaf(h1.y, wv.y, acc[1][u]);
          acc[1][u] = fmaf(h1.z, wv.z, acc[1][u]);
          acc[1][u] = fmaf(h1.w, wv.w, acc[1][u]);
        }
      }
    }
  }
#pragma unroll
  for (int q = 0; q < 2; ++q) {
    const int b = b0 + 32 * q;
    const int j = j0 + jj;
    float gv[4];
#pragma unroll
    for (int u = 0; u < 4; ++u) {
      size_t idx = ((size_t)t * 64 + b) * 4096 + (size_t)u * 1024 + j;
      float xv;
      if constexpr (std::is_same_v<XG_T, float>) xv = xg[idx];
      else xv = __bfloat162float(xg[idx]);
      gv[u] = acc[q][u] + xv;
    }
    const float ig = sigmoidf_(gv[0]);
    const float fg = sigmoidf_(gv[1]);
    const float gg = tanhf(gv[2]);
    const float og = sigmoidf_(gv[3]);
    const float cold = (t > 0) ? c[b * 1024 + j] : 0.0f;
    const float cn = fmaf(fg, cold, ig * gg);
    c[b * 1024 + j] = cn;
    out[((size_t)t * 64 + b) * 1024 + j] = og * tanhf(cn);
  }
}

// ---------------- tail: [h_final | c_final] --------------------------------
__global__ void tail_copy_kernel(const float* __restrict__ hfin,
                                 const float* __restrict__ c,
                                 float* __restrict__ dst) {
  int i = blockIdx.x * 256 + threadIdx.x;   // 0 .. 131071
  dst[i] = (i < B_DIM * H_DIM) ? hfin[i] : c[i - B_DIM * H_DIM];
}

extern "C" void kernel_launch(void* const* d_in, const int* in_sizes, int n_in,
                              void* d_out, int out_size, void* d_ws, size_t ws_size,
                              hipStream_t stream) {
  const float* x  = (const float*)d_in[0];
  const float* Wx = (const float*)d_in[1];
  const float* Wh = (const float*)d_in[2];
  const float* bh = (const float*)d_in[3];
  float* out = (float*)d_out;

  const size_t xg_elems = (size_t)T_DIM * B_DIM * G_DIM;       // 134,217,728
  const size_t c_bytes  = (size_t)B_DIM * H_DIM * sizeof(float);
  char* ws = (char*)d_ws;

  const dim3 g1(T_DIM * B_DIM / 64, G_DIM / 64);               // 512 x 64

  if (ws_size >= xg_elems * sizeof(float) + c_bytes) {
    // f32 xg path
    float* xg = (float*)ws;
    float* c  = (float*)(ws + xg_elems * sizeof(float));
    xg_gemm_kernel<float><<<g1, 256, 0, stream>>>(x, Wx, bh, xg);
    for (int t = 0; t < T_DIM; ++t)
      lstm_step_kernel<float><<<128, 256, 0, stream>>>(xg, Wh, out, c, t);
    tail_copy_kernel<<<512, 256, 0, stream>>>(
        out + (size_t)(T_DIM - 1) * B_DIM * H_DIM, c,
        out + (size_t)T_DIM * B_DIM * H_DIM);
  } else {
    // bf16 xg fallback (half the workspace)
    __hip_bfloat16* xg = (__hip_bfloat16*)ws;
    float* c = (float*)(ws + xg_elems * sizeof(__hip_bfloat16));
    xg_gemm_kernel<__hip_bfloat16><<<g1, 256, 0, stream>>>(x, Wx, bh, xg);
    for (int t = 0; t < T_DIM; ++t)
      lstm_step_kernel<__hip_bfloat16><<<128, 256, 0, stream>>>(xg, Wh, out, c, t);
    tail_copy_kernel<<<512, 256, 0, stream>>>(
        out + (size_t)(T_DIM - 1) * B_DIM * H_DIM, c,
        out + (size_t)T_DIM * B_DIM * H_DIM);
  }
}

// Round 2
// 7588.944 us; speedup vs baseline: 8.5655x; 8.5655x over previous
//
#include <hip/hip_runtime.h>
#include <cstddef>
#include <cstdint>

// LSTM T=512 B=64 D=1024 H=1024.
//   Phase 1: xg = x @ Wx^T + bh  -> bf16, MFMA 128x128-tile GEMM (f32 staged->bf16 LDS)
//   Phase 2: 512 sequential step kernels; gates = xg[t] + h_{t-1} @ Wh^T via MFMA,
//            fragments loaded straight from L2 (h=128KiB, Wh slice hot), cell update in-register.
// d_out = [outputs(T,B,H) | h(B,H) | c(B,H)] f32.

#define T_DIM 512
#define B_DIM 64
#define H_DIM 1024
#define G_DIM 4096

typedef short short8 __attribute__((ext_vector_type(8)));
typedef float f32x4 __attribute__((ext_vector_type(4)));
typedef unsigned short ushort_t;

__device__ __forceinline__ ushort_t f2b(float f) {   // f32 -> bf16 RNE
  union { float f; unsigned u; } v; v.f = f;
  unsigned r = v.u + 0x7fffu + ((v.u >> 16) & 1u);
  return (ushort_t)(r >> 16);
}
__device__ __forceinline__ float b2f(ushort_t u) {
  union { unsigned u; float f; } v; v.u = ((unsigned)u) << 16;
  return v.f;
}
__device__ __forceinline__ float sigmoidf_(float x) { return 1.0f / (1.0f + __expf(-x)); }

// ---------------------------------------------------------------------------
// convert f32 -> bf16 (Wh), 8 elems/thread
__global__ __launch_bounds__(256) void convert_bf16_kernel(
    const float* __restrict__ src, ushort_t* __restrict__ dst, int n8) {
  int i = blockIdx.x * 256 + threadIdx.x;
  if (i >= n8) return;
  float4 v0 = *(const float4*)&src[(size_t)i * 8];
  float4 v1 = *(const float4*)&src[(size_t)i * 8 + 4];
  ushort_t p[8] = {f2b(v0.x), f2b(v0.y), f2b(v0.z), f2b(v0.w),
                   f2b(v1.x), f2b(v1.y), f2b(v1.z), f2b(v1.w)};
  *(short8*)&dst[(size_t)i * 8] = *(const short8*)p;
}

// ---------------------------------------------------------------------------
// MFMA GEMM: C[m][n] = bf16( sum_k x[m][k]*Wx[n][k] + bh[n] )
// M=32768 N=4096 K=1024. 128x128 block tile, 256 thr (4 waves 2x2), BK=64.
// LDS tiles XOR-swizzled: byte ^= (row&7)<<4  (T2; ds_read_b128 ~conflict-free).
__global__ __launch_bounds__(256) void xg_gemm_mfma(
    const float* __restrict__ A,    // x  [M][1024]
    const float* __restrict__ Bw,   // Wx [4096][1024]
    const float* __restrict__ bh,   // [4096]
    ushort_t* __restrict__ C) {     // xg bf16 [M][4096]
  __shared__ ushort_t As[128 * 64];
  __shared__ ushort_t Bs[128 * 64];
  const int tid = threadIdx.x;
  const int lane = tid & 63;
  const int w = tid >> 6;
  const int wm = w >> 1, wn = w & 1;
  const size_t m0 = (size_t)blockIdx.x * 128;
  const int n0 = blockIdx.y * 128;
  const int r = tid >> 1;             // staging row 0..127
  const int kb = (tid & 1) * 32;      // staging k-half

  f32x4 acc[4][4];
#pragma unroll
  for (int i = 0; i < 4; ++i)
#pragma unroll
    for (int j = 0; j < 4; ++j) acc[i][j] = 0.0f;

  const int lr = lane & 15;           // frag row/col within 16
  const int lk = (lane >> 4) * 8;     // frag k offset (8 contiguous bf16)

  for (int k0 = 0; k0 < 1024; k0 += 64) {
    __syncthreads();
#pragma unroll
    for (int i = 0; i < 4; ++i) {
      const int kk = kb + i * 8;
      float4 a0 = *(const float4*)&A[(m0 + r) * 1024 + k0 + kk];
      float4 a1 = *(const float4*)&A[(m0 + r) * 1024 + k0 + kk + 4];
      ushort_t pa[8] = {f2b(a0.x), f2b(a0.y), f2b(a0.z), f2b(a0.w),
                        f2b(a1.x), f2b(a1.y), f2b(a1.z), f2b(a1.w)};
      float4 b0 = *(const float4*)&Bw[(size_t)(n0 + r) * 1024 + k0 + kk];
      float4 b1 = *(const float4*)&Bw[(size_t)(n0 + r) * 1024 + k0 + kk + 4];
      ushort_t pb[8] = {f2b(b0.x), f2b(b0.y), f2b(b0.z), f2b(b0.w),
                        f2b(b1.x), f2b(b1.y), f2b(b1.z), f2b(b1.w)};
      const int byte = (r * 128 + kk * 2) ^ ((r & 7) << 4);
      *(short8*)((char*)As + byte) = *(const short8*)pa;
      *(short8*)((char*)Bs + byte) = *(const short8*)pb;
    }
    __syncthreads();
#pragma unroll
    for (int kk = 0; kk < 64; kk += 32) {
      short8 af[4], bf[4];
#pragma unroll
      for (int mf = 0; mf < 4; ++mf) {
        const int row = wm * 64 + mf * 16 + lr;
        const int byte = (row * 128 + (kk + lk) * 2) ^ ((row & 7) << 4);
        af[mf] = *(const short8*)((const char*)As + byte);
      }
#pragma unroll
      for (int nf = 0; nf < 4; ++nf) {
        const int row = wn * 64 + nf * 16 + lr;
        const int byte = (row * 128 + (kk + lk) * 2) ^ ((row & 7) << 4);
        bf[nf] = *(const short8*)((const char*)Bs + byte);
      }
#pragma unroll
      for (int mf = 0; mf < 4; ++mf)
#pragma unroll
        for (int nf = 0; nf < 4; ++nf)
          acc[mf][nf] = __builtin_amdgcn_mfma_f32_16x16x32_bf16(
              af[mf], bf[nf], acc[mf][nf], 0, 0, 0);
    }
  }
  // epilogue: +bias, store bf16.  C/D frag: col=lane&15, row=(lane>>4)*4+reg
#pragma unroll
  for (int nf = 0; nf < 4; ++nf) {
    const int col = n0 + wn * 64 + nf * 16 + lr;
    const float bias = bh[col];
#pragma unroll
    for (int mf = 0; mf < 4; ++mf) {
      const size_t row0 = m0 + wm * 64 + mf * 16 + (lane >> 4) * 4;
#pragma unroll
      for (int rr = 0; rr < 4; ++rr)
        C[(row0 + rr) * 4096 + col] = f2b(acc[mf][nf][rr] + bias);
    }
  }
}

// ---------------------------------------------------------------------------
// Per-step recurrent kernel, MFMA, 256 blocks x 1 wave.
// Block b: wave owns batch rows [w*16, w*16+16), j-cols [j0, j0+16), all 4 gates.
//   j0 = (b>>2)*16, w = b&3.
// A-frag: h_prev rows (bf16, global);  B-frag[g]: Wh rows g*1024+j0+(lane&15).
// C-frag regs give each lane i,f,g,o for its (batch,j) -> in-register cell update.
__global__ __launch_bounds__(64) void lstm_step_mfma(
    const ushort_t* __restrict__ xg,     // [T*64][4096] bf16 (bias folded)
    const ushort_t* __restrict__ Whb,    // [4096][1024] bf16
    const ushort_t* __restrict__ hprev,  // [64][1024] bf16
    ushort_t* __restrict__ hcur,         // [64][1024] bf16
    float* __restrict__ c,               // [64][1024] f32
    float* __restrict__ out,             // [T][64][1024] f32
    int t) {
  const int lane = threadIdx.x;
  const int j0 = (blockIdx.x >> 2) * 16;
  const int w  = blockIdx.x & 3;
  const int lr = lane & 15;
  const int ko = (lane >> 4) * 8;

  f32x4 acc[4];
#pragma unroll
  for (int g = 0; g < 4; ++g) acc[g] = 0.0f;

  if (t > 0) {
    const int arow = w * 16 + lr;
    const char* hp = (const char*)(hprev + (size_t)arow * 1024 + ko);
    const char* wp0 = (const char*)(Whb + (size_t)(0 * 1024 + j0 + lr) * 1024 + ko);
    const char* wp1 = (const char*)(Whb + (size_t)(1 * 1024 + j0 + lr) * 1024 + ko);
    const char* wp2 = (const char*)(Whb + (size_t)(2 * 1024 + j0 + lr) * 1024 + ko);
    const char* wp3 = (const char*)(Whb + (size_t)(3 * 1024 + j0 + lr) * 1024 + ko);
#pragma unroll 8
    for (int ks = 0; ks < 32; ++ks) {
      const int off = ks * 64;  // 32 bf16 = 64B per k-step
      short8 a  = *(const short8*)(hp + off);
      short8 b0 = *(const short8*)(wp0 + off);
      short8 b1 = *(const short8*)(wp1 + off);
      short8 b2 = *(const short8*)(wp2 + off);
      short8 b3 = *(const short8*)(wp3 + off);
      acc[0] = __builtin_amdgcn_mfma_f32_16x16x32_bf16(a, b0, acc[0], 0, 0, 0);
      acc[1] = __builtin_amdgcn_mfma_f32_16x16x32_bf16(a, b1, acc[1], 0, 0, 0);
      acc[2] = __builtin_amdgcn_mfma_f32_16x16x32_bf16(a, b2, acc[2], 0, 0, 0);
      acc[3] = __builtin_amdgcn_mfma_f32_16x16x32_bf16(a, b3, acc[3], 0, 0, 0);
    }
  }
  // epilogue: lane holds gates for j = j0+lr, batches (lane>>4)*4 + w*16 + rr
  const int j = j0 + lr;
  const int rb = w * 16 + (lane >> 4) * 4;
#pragma unroll
  for (int rr = 0; rr < 4; ++rr) {
    const int b = rb + rr;
    const size_t gidx = ((size_t)t * 64 + b) * 4096 + j;
    const float pi = acc[0][rr] + b2f(xg[gidx]);
    const float pf = acc[1][rr] + b2f(xg[gidx + 1024]);
    const float pg = acc[2][rr] + b2f(xg[gidx + 2048]);
    const float po = acc[3][rr] + b2f(xg[gidx + 3072]);
    const float ig = sigmoidf_(pi);
    const float fg = sigmoidf_(pf);
    const float gg = tanhf(pg);
    const float og = sigmoidf_(po);
    const int ci = b * 1024 + j;
    const float cold = (t > 0) ? c[ci] : 0.0f;
    const float cn = fmaf(fg, cold, ig * gg);
    c[ci] = cn;
    const float h = og * tanhf(cn);
    out[((size_t)t * 64 + b) * 1024 + j] = h;
    hcur[ci] = f2b(h);
  }
}

// ---------------------------------------------------------------------------
__global__ void tail_copy_kernel(const float* __restrict__ hfin,
                                 const float* __restrict__ c,
                                 float* __restrict__ dst) {
  int i = blockIdx.x * 256 + threadIdx.x;  // 0 .. 131071
  dst[i] = (i < B_DIM * H_DIM) ? hfin[i] : c[i - B_DIM * H_DIM];
}

// ===========================================================================
// Fallback (round-1, known-correct): used only if ws is too small for the
// MFMA path (needs xg bf16 256Mi + Wh 8Mi + 2x hb + c).
__global__ __launch_bounds__(256) void xg_gemm_old(
    const float* __restrict__ A, const float* __restrict__ Bw,
    const float* __restrict__ bh, ushort_t* __restrict__ C) {
  __shared__ float As[16][68];
  __shared__ float Bs[16][68];
  const int tid = threadIdx.x;
  const size_t m0 = (size_t)blockIdx.x * 64;
  const int n0 = blockIdx.y * 64;
  const int tx = tid & 15, ty = tid >> 4, lm = tid >> 2, lk = (tid & 3) * 4;
  float acc[4][4] = {};
  for (int k0 = 0; k0 < 1024; k0 += 16) {
    __syncthreads();
    float4 av = *(const float4*)&A[(m0 + lm) * 1024 + k0 + lk];
    float4 bv = *(const float4*)&Bw[(size_t)(n0 + lm) * 1024 + k0 + lk];
    As[lk + 0][lm] = av.x; As[lk + 1][lm] = av.y;
    As[lk + 2][lm] = av.z; As[lk + 3][lm] = av.w;
    Bs[lk + 0][lm] = bv.x; Bs[lk + 1][lm] = bv.y;
    Bs[lk + 2][lm] = bv.z; Bs[lk + 3][lm] = bv.w;
    __syncthreads();
#pragma unroll
    for (int k = 0; k < 16; ++k) {
      float a[4], b[4];
      *(float4*)a = *(const float4*)&As[k][ty * 4];
      *(float4*)b = *(const float4*)&Bs[k][tx * 4];
#pragma unroll
      for (int i = 0; i < 4; ++i)
#pragma unroll
        for (int j = 0; j < 4; ++j) acc[i][j] = fmaf(a[i], b[j], acc[i][j]);
    }
  }
#pragma unroll
  for (int i = 0; i < 4; ++i) {
    size_t row = m0 + ty * 4 + i;
#pragma unroll
    for (int j = 0; j < 4; ++j)
      C[row * 4096 + n0 + tx * 4 + j] = f2b(acc[i][j] + bh[n0 + tx * 4 + j]);
  }
}

__global__ __launch_bounds__(256) void lstm_step_old(
    const ushort_t* __restrict__ xg, const float* __restrict__ Wh,
    float* __restrict__ out, float* __restrict__ c, int t) {
  __shared__ float hs[64][68];
  __shared__ float wt[32][64];
  const int tid = threadIdx.x;
  const int j0 = blockIdx.x * 8;
  const int jj = tid & 7;
  const int b0 = tid >> 3;
  float acc[2][4] = {};
  if (t > 0) {
    const float* __restrict__ hprev = out + (size_t)(t - 1) * (B_DIM * H_DIM);
    for (int k0 = 0; k0 < 1024; k0 += 64) {
      __syncthreads();
#pragma unroll
      for (int i = 0; i < 16; ++i) {
        int e = tid + 256 * i; hs[e >> 6][e & 63] = hprev[(e >> 6) * 1024 + k0 + (e & 63)];
      }
#pragma unroll
      for (int i = 0; i < 8; ++i) {
        int e = tid + 256 * i; int rr = e >> 6, kk = e & 63;
        wt[rr][kk] = Wh[(size_t)((rr >> 3) * 1024 + j0 + (rr & 7)) * 1024 + k0 + kk];
      }
      __syncthreads();
#pragma unroll
      for (int kq = 0; kq < 16; ++kq) {
        float4 h0 = *(const float4*)&hs[b0][kq * 4];
        float4 h1 = *(const float4*)&hs[b0 + 32][kq * 4];
#pragma unroll
        for (int u = 0; u < 4; ++u) {
          float4 wv = *(const float4*)&wt[u * 8 + jj][kq * 4];
          acc[0][u] = fmaf(h0.x, wv.x, acc[0][u]); acc[0][u] = fmaf(h0.y, wv.y, acc[0][u]);
          acc[0][u] = fmaf(h0.z, wv.z, acc[0][u]); acc[0][u] = fmaf(h0.w, wv.w, acc[0][u]);
          acc[1][u] = fmaf(h1.x, wv.x, acc[1][u]); acc[1][u] = fmaf(h1.y, wv.y, acc[1][u]);
          acc[1][u] = fmaf(h1.z, wv.z, acc[1][u]); acc[1][u] = fmaf(h1.w, wv.w, acc[1][u]);
        }
      }
    }
  }
#pragma unroll
  for (int q = 0; q < 2; ++q) {
    const int b = b0 + 32 * q;
    const int j = j0 + jj;
    float gv[4];
#pragma unroll
    for (int u = 0; u < 4; ++u)
      gv[u] = acc[q][u] + b2f(xg[((size_t)t * 64 + b) * 4096 + (size_t)u * 1024 + j]);
    const float ig = sigmoidf_(gv[0]);
    const float fg = sigmoidf_(gv[1]);
    const float gg = tanhf(gv[2]);
    const float og = sigmoidf_(gv[3]);
    const float cold = (t > 0) ? c[b * 1024 + j] : 0.0f;
    const float cn = fmaf(fg, cold, ig * gg);
    c[b * 1024 + j] = cn;
    out[((size_t)t * 64 + b) * 1024 + j] = og * tanhf(cn);
  }
}

// ===========================================================================
extern "C" void kernel_launch(void* const* d_in, const int* in_sizes, int n_in,
                              void* d_out, int out_size, void* d_ws, size_t ws_size,
                              hipStream_t stream) {
  const float* x  = (const float*)d_in[0];
  const float* Wx = (const float*)d_in[1];
  const float* Wh = (const float*)d_in[2];
  const float* bh = (const float*)d_in[3];
  float* out = (float*)d_out;

  const size_t xg_bytes = (size_t)T_DIM * B_DIM * G_DIM * 2;   // 256 MiB
  const size_t wh_bytes = (size_t)G_DIM * H_DIM * 2;           // 8 MiB
  const size_t hb_bytes = (size_t)B_DIM * H_DIM * 2;           // 128 KiB
  const size_t c_bytes  = (size_t)B_DIM * H_DIM * 4;           // 256 KiB
  const size_t need = xg_bytes + wh_bytes + 2 * hb_bytes + c_bytes;
  char* ws = (char*)d_ws;

  if (ws_size >= need) {
    ushort_t* xg  = (ushort_t*)ws;
    ushort_t* Whb = (ushort_t*)(ws + xg_bytes);
    ushort_t* hb0 = (ushort_t*)(ws + xg_bytes + wh_bytes);
    ushort_t* hb1 = (ushort_t*)(ws + xg_bytes + wh_bytes + hb_bytes);
    float*    c   = (float*)(ws + xg_bytes + wh_bytes + 2 * hb_bytes);

    convert_bf16_kernel<<<(G_DIM * H_DIM / 8 + 255) / 256, 256, 0, stream>>>(
        Wh, Whb, G_DIM * H_DIM / 8);
    xg_gemm_mfma<<<dim3(T_DIM * B_DIM / 128, G_DIM / 128), 256, 0, stream>>>(
        x, Wx, bh, xg);
    for (int t = 0; t < T_DIM; ++t) {
      ushort_t* hc = (t & 1) ? hb1 : hb0;
      ushort_t* hp = (t & 1) ? hb0 : hb1;
      lstm_step_mfma<<<256, 64, 0, stream>>>(xg, Whb, hp, hc, c, out, t);
    }
    tail_copy_kernel<<<512, 256, 0, stream>>>(
        out + (size_t)(T_DIM - 1) * B_DIM * H_DIM, c,
        out + (size_t)T_DIM * B_DIM * H_DIM);
  } else {
    // round-1 fallback (bf16 xg, f32 recurrence)
    ushort_t* xg = (ushort_t*)ws;
    float* c = (float*)(ws + xg_bytes);
    xg_gemm_old<<<dim3(T_DIM * B_DIM / 64, G_DIM / 64), 256, 0, stream>>>(x, Wx, bh, xg);
    for (int t = 0; t < T_DIM; ++t)
      lstm_step_old<<<128, 256, 0, stream>>>(xg, Wh, out, c, t);
    tail_copy_kernel<<<512, 256, 0, stream>>>(
        out + (size_t)(T_DIM - 1) * B_DIM * H_DIM, c,
        out + (size_t)T_DIM * B_DIM * H_DIM);
  }
}